// Round 4
// baseline (228.744 us; speedup 1.0000x reference)
//
#include <hip/hip_runtime.h>

#define NSEG 6
#define NBLOCKS 2048
#define NTHREADS 256

__device__ __forceinline__ void consume4(const float4 p, const int4 t, const int4 w,
                                         float (&ps)[NSEG], unsigned long long& c64) {
    int s0 = t.x * 3 + w.x;
    int s1 = t.y * 3 + w.y;
    int s2 = t.z * 3 + w.z;
    int s3 = t.w * 3 + w.w;
    c64 += (1ull << (s0 << 3)) + (1ull << (s1 << 3)) +
           (1ull << (s2 << 3)) + (1ull << (s3 << 3));
#pragma unroll
    for (int s = 0; s < NSEG; ++s) {
        float v = (s0 == s ? p.x : 0.f);
        v += (s1 == s ? p.y : 0.f);
        v += (s2 == s ? p.z : 0.f);
        v += (s3 == s ? p.w : 0.f);
        ps[s] += v;
    }
}

#define FLUSH_C64()                                                   \
    do {                                                              \
        _Pragma("unroll")                                             \
        for (int s = 0; s < NSEG; ++s)                                \
            cn[s] += (int)((c64 >> (8 * s)) & 0xFFull);               \
        c64 = 0ull;                                                   \
        fl = 0;                                                       \
    } while (0)

__global__ __launch_bounds__(NTHREADS, 8) void wdice_partial(
    const float4* __restrict__ pred,
    const int4* __restrict__ tgt,
    const int4* __restrict__ wt,
    int nvec,
    float* __restrict__ out_ws)     // [NBLOCKS][12]: 6 psum then 6 cnt
{
    float ps[NSEG];
    int cn[NSEG];
#pragma unroll
    for (int s = 0; s < NSEG; ++s) { ps[s] = 0.f; cn[s] = 0; }
    unsigned long long c64 = 0ull;
    int fl = 0;

    const int tid = threadIdx.x;
    const int stride = NBLOCKS * NTHREADS;   // 524288 vec4 positions
    int i = blockIdx.x * NTHREADS + tid;

    // 2-stage software pipeline with named register buffers A/B:
    // prefetch one batch while consuming the other. Keeps 3 loads in
    // flight per wave at all times; full occupancy hides the rest.
    float4 pA, pB;
    int4 tA, tB, wA, wB;

    bool validA = (i < nvec);
    if (validA) { pA = pred[i]; tA = tgt[i]; wA = wt[i]; }
    int j = i + stride;

    while (true) {
        bool validB = (j < nvec);
        if (validB) { pB = pred[j]; tB = tgt[j]; wB = wt[j]; }
        if (validA) {
            consume4(pA, tA, wA, ps, c64);
            if (++fl == 62) FLUSH_C64();
        }
        if (!validB) break;

        i = j + stride;
        validA = (i < nvec);
        if (validA) { pA = pred[i]; tA = tgt[i]; wA = wt[i]; }
        consume4(pB, tB, wB, ps, c64);
        if (++fl == 62) FLUSH_C64();
        if (!validA) break;

        j = i + stride;
    }
    FLUSH_C64();

    // pack counts into 16-bit fields: per-thread <=128, block sum <=32768
    unsigned int pk0 = (unsigned)cn[0] | ((unsigned)cn[1] << 16);
    unsigned int pk1 = (unsigned)cn[2] | ((unsigned)cn[3] << 16);
    unsigned int pk2 = (unsigned)cn[4] | ((unsigned)cn[5] << 16);

    // wave (64-lane) shuffle reduction: 6 floats + 3 packed uints
#pragma unroll
    for (int off = 32; off > 0; off >>= 1) {
#pragma unroll
        for (int s = 0; s < NSEG; ++s) ps[s] += __shfl_down(ps[s], off, 64);
        pk0 += __shfl_down(pk0, off, 64);
        pk1 += __shfl_down(pk1, off, 64);
        pk2 += __shfl_down(pk2, off, 64);
    }

    __shared__ float lps[4][NSEG];
    __shared__ unsigned int lpk[4][3];
    int lane = tid & 63;
    int wave = tid >> 6;
    if (lane == 0) {
#pragma unroll
        for (int s = 0; s < NSEG; ++s) lps[wave][s] = ps[s];
        lpk[wave][0] = pk0; lpk[wave][1] = pk1; lpk[wave][2] = pk2;
    }
    __syncthreads();
    if (tid == 0) {
        unsigned int bk0 = lpk[0][0] + lpk[1][0] + lpk[2][0] + lpk[3][0];
        unsigned int bk1 = lpk[0][1] + lpk[1][1] + lpk[2][1] + lpk[3][1];
        unsigned int bk2 = lpk[0][2] + lpk[1][2] + lpk[2][2] + lpk[3][2];
#pragma unroll
        for (int s = 0; s < NSEG; ++s) {
            float tps = lps[0][s] + lps[1][s] + lps[2][s] + lps[3][s];
            out_ws[blockIdx.x * 12 + s] = tps;
        }
        out_ws[blockIdx.x * 12 + 6]  = (float)(bk0 & 0xFFFF);
        out_ws[blockIdx.x * 12 + 7]  = (float)(bk0 >> 16);
        out_ws[blockIdx.x * 12 + 8]  = (float)(bk1 & 0xFFFF);
        out_ws[blockIdx.x * 12 + 9]  = (float)(bk1 >> 16);
        out_ws[blockIdx.x * 12 + 10] = (float)(bk2 & 0xFFFF);
        out_ws[blockIdx.x * 12 + 11] = (float)(bk2 >> 16);
    }
}

__global__ __launch_bounds__(NTHREADS) void wdice_final(
    const float* __restrict__ ws,   // [nrows][12]
    int nrows,
    float* __restrict__ out)
{
    double a[12];
#pragma unroll
    for (int r = 0; r < 12; ++r) a[r] = 0.0;

    for (int row = threadIdx.x; row < nrows; row += blockDim.x) {
#pragma unroll
        for (int r = 0; r < 12; ++r)
            a[r] += (double)ws[row * 12 + r];
    }

#pragma unroll
    for (int r = 0; r < 12; ++r) {
#pragma unroll
        for (int off = 32; off > 0; off >>= 1)
            a[r] += __shfl_down(a[r], off, 64);
    }

    __shared__ double l[4][12];
    int lane = threadIdx.x & 63;
    int wave = threadIdx.x >> 6;
    if (lane == 0) {
#pragma unroll
        for (int r = 0; r < 12; ++r) l[wave][r] = a[r];
    }
    __syncthreads();
    if (threadIdx.x == 0) {
        double numer = 0.0, denom = 0.0;
#pragma unroll
        for (int s = 0; s < NSEG; ++s) {
            double tps = l[0][s] + l[1][s] + l[2][s] + l[3][s];
            double tcn = l[0][s + 6] + l[1][s + 6] + l[2][s + 6] + l[3][s + 6];
            if (tcn > 0.0) {
                double inv_n2 = 1.0 / (tcn * tcn);
                numer += tps * inv_n2;
                denom += (tps + tcn) * inv_n2;
            }
        }
        out[0] = (float)(1.0 - 2.0 * numer / denom);
    }
}

extern "C" void kernel_launch(void* const* d_in, const int* in_sizes, int n_in,
                              void* d_out, int out_size, void* d_ws, size_t ws_size,
                              hipStream_t stream) {
    const float4* pred = (const float4*)d_in[0];
    const int4* tgt = (const int4*)d_in[1];
    const int4* wt = (const int4*)d_in[2];
    int n = in_sizes[0];
    int nvec = n / 4;

    float* ws = (float*)d_ws;  // NBLOCKS * 12 floats

    wdice_partial<<<NBLOCKS, NTHREADS, 0, stream>>>(pred, tgt, wt, nvec, ws);
    wdice_final<<<1, NTHREADS, 0, stream>>>(ws, NBLOCKS, (float*)d_out);
}

// Round 5
// 153.018 us; speedup vs baseline: 1.4949x; 1.4949x over previous
//
#include <hip/hip_runtime.h>

#define NSEG 6
#define NBLOCKS 1536
#define NTHREADS 256

typedef __attribute__((address_space(3))) void* lds_vp;
typedef const __attribute__((address_space(1))) void* gl_vp;

#define GLOAD16(g, l) __builtin_amdgcn_global_load_lds((gl_vp)(g), (lds_vp)(l), 16, 0, 0)

__device__ __forceinline__ void consume4(const float4 p, const int4 t, const int4 w,
                                         float (&ps)[NSEG], unsigned long long& c64) {
    int s0 = t.x * 3 + w.x;
    int s1 = t.y * 3 + w.y;
    int s2 = t.z * 3 + w.z;
    int s3 = t.w * 3 + w.w;
    c64 += (1ull << (s0 << 3)) + (1ull << (s1 << 3)) +
           (1ull << (s2 << 3)) + (1ull << (s3 << 3));
#pragma unroll
    for (int s = 0; s < NSEG; ++s) {
        float v = (s0 == s ? p.x : 0.f);
        v += (s1 == s ? p.y : 0.f);
        v += (s2 == s ? p.z : 0.f);
        v += (s3 == s ? p.w : 0.f);
        ps[s] += v;
    }
}

__global__ __launch_bounds__(NTHREADS) void wdice_partial(
    const float4* __restrict__ pred,
    const int4* __restrict__ tgt,
    const int4* __restrict__ wt,
    int nvec,
    float* __restrict__ out_ws)     // [NBLOCKS][12]: 6 psum then 6 cnt
{
    __shared__ float4 bp[2][NTHREADS];
    __shared__ int4   bt[2][NTHREADS];
    __shared__ int4   bw[2][NTHREADS];

    const int tid = threadIdx.x;
    const int lane = tid & 63;
    const int wv = tid >> 6;
    const int G = NBLOCKS * NTHREADS;

    float ps[NSEG];
    int cn[NSEG];
#pragma unroll
    for (int s = 0; s < NSEG; ++s) { ps[s] = 0.f; cn[s] = 0; }
    unsigned long long c64 = 0ull;
    int fl = 0;

    // wave-uniform vec4 base for step 0; lane handles vbase+lane
    const int vbase = blockIdx.x * NTHREADS + wv * 64;
    int idx = vbase + lane;                 // this lane's vec4 index at step k
    int k = 0;
    bool valid = (vbase + 64) <= nvec;      // whole wave's chunk in range?

    if (valid) {
        GLOAD16(pred + idx, &bp[0][wv * 64]);
        GLOAD16(tgt + idx,  &bt[0][wv * 64]);
        GLOAD16(wt + idx,   &bw[0][wv * 64]);
    }

    while (valid) {
        const int b = k & 1;
        const int nidx = idx + G;
        const bool validn = (vbase + (k + 1) * G + 64) <= nvec;
        if (validn) {
            GLOAD16(pred + nidx, &bp[b ^ 1][wv * 64]);
            GLOAD16(tgt + nidx,  &bt[b ^ 1][wv * 64]);
            GLOAD16(wt + nidx,   &bw[b ^ 1][wv * 64]);
            asm volatile("s_waitcnt vmcnt(3)" ::: "memory");  // stage k done, k+1 in flight
        } else {
            asm volatile("s_waitcnt vmcnt(0)" ::: "memory");
        }
        float4 p = bp[b][tid];
        int4 t = bt[b][tid];
        int4 w = bw[b][tid];
        consume4(p, t, w, ps, c64);
        if (++fl == 60) {   // 60*4=240 <= 255: no 8-bit field overflow
#pragma unroll
            for (int s = 0; s < NSEG; ++s) cn[s] += (int)((c64 >> (8 * s)) & 0xFFull);
            c64 = 0ull; fl = 0;
        }
        idx = nidx; valid = validn; ++k;
    }
#pragma unroll
    for (int s = 0; s < NSEG; ++s) cn[s] += (int)((c64 >> (8 * s)) & 0xFFull);
    c64 = 0ull;

    // scalar tail: last nvec%64 vec4s (empty for the bench shape)
    const int tail = nvec & ~63;
    for (int i = tail + blockIdx.x * NTHREADS + tid; i < nvec; i += G) {
        float4 p = pred[i];
        int4 t = tgt[i];
        int4 w = wt[i];
        consume4(p, t, w, ps, c64);
    }
#pragma unroll
    for (int s = 0; s < NSEG; ++s) cn[s] += (int)((c64 >> (8 * s)) & 0xFFull);

    // pack counts into 16-bit fields: per-thread <=128, block sum <=32768
    unsigned int pk0 = (unsigned)cn[0] | ((unsigned)cn[1] << 16);
    unsigned int pk1 = (unsigned)cn[2] | ((unsigned)cn[3] << 16);
    unsigned int pk2 = (unsigned)cn[4] | ((unsigned)cn[5] << 16);

#pragma unroll
    for (int off = 32; off > 0; off >>= 1) {
#pragma unroll
        for (int s = 0; s < NSEG; ++s) ps[s] += __shfl_down(ps[s], off, 64);
        pk0 += __shfl_down(pk0, off, 64);
        pk1 += __shfl_down(pk1, off, 64);
        pk2 += __shfl_down(pk2, off, 64);
    }

    __shared__ float lps[4][NSEG];
    __shared__ unsigned int lpk[4][3];
    if (lane == 0) {
#pragma unroll
        for (int s = 0; s < NSEG; ++s) lps[wv][s] = ps[s];
        lpk[wv][0] = pk0; lpk[wv][1] = pk1; lpk[wv][2] = pk2;
    }
    __syncthreads();
    if (tid == 0) {
        unsigned int bk0 = lpk[0][0] + lpk[1][0] + lpk[2][0] + lpk[3][0];
        unsigned int bk1 = lpk[0][1] + lpk[1][1] + lpk[2][1] + lpk[3][1];
        unsigned int bk2 = lpk[0][2] + lpk[1][2] + lpk[2][2] + lpk[3][2];
#pragma unroll
        for (int s = 0; s < NSEG; ++s) {
            float tps = lps[0][s] + lps[1][s] + lps[2][s] + lps[3][s];
            out_ws[blockIdx.x * 12 + s] = tps;
        }
        out_ws[blockIdx.x * 12 + 6]  = (float)(bk0 & 0xFFFF);
        out_ws[blockIdx.x * 12 + 7]  = (float)(bk0 >> 16);
        out_ws[blockIdx.x * 12 + 8]  = (float)(bk1 & 0xFFFF);
        out_ws[blockIdx.x * 12 + 9]  = (float)(bk1 >> 16);
        out_ws[blockIdx.x * 12 + 10] = (float)(bk2 & 0xFFFF);
        out_ws[blockIdx.x * 12 + 11] = (float)(bk2 >> 16);
    }
}

__global__ __launch_bounds__(NTHREADS) void wdice_final(
    const float* __restrict__ ws,   // [nrows][12]
    int nrows,
    float* __restrict__ out)
{
    double a[12];
#pragma unroll
    for (int r = 0; r < 12; ++r) a[r] = 0.0;

    for (int row = threadIdx.x; row < nrows; row += blockDim.x) {
#pragma unroll
        for (int r = 0; r < 12; ++r)
            a[r] += (double)ws[row * 12 + r];
    }

#pragma unroll
    for (int r = 0; r < 12; ++r) {
#pragma unroll
        for (int off = 32; off > 0; off >>= 1)
            a[r] += __shfl_down(a[r], off, 64);
    }

    __shared__ double l[4][12];
    int lane = threadIdx.x & 63;
    int wave = threadIdx.x >> 6;
    if (lane == 0) {
#pragma unroll
        for (int r = 0; r < 12; ++r) l[wave][r] = a[r];
    }
    __syncthreads();
    if (threadIdx.x == 0) {
        double numer = 0.0, denom = 0.0;
#pragma unroll
        for (int s = 0; s < NSEG; ++s) {
            double tps = l[0][s] + l[1][s] + l[2][s] + l[3][s];
            double tcn = l[0][s + 6] + l[1][s + 6] + l[2][s + 6] + l[3][s + 6];
            if (tcn > 0.0) {
                double inv_n2 = 1.0 / (tcn * tcn);
                numer += tps * inv_n2;
                denom += (tps + tcn) * inv_n2;
            }
        }
        out[0] = (float)(1.0 - 2.0 * numer / denom);
    }
}

extern "C" void kernel_launch(void* const* d_in, const int* in_sizes, int n_in,
                              void* d_out, int out_size, void* d_ws, size_t ws_size,
                              hipStream_t stream) {
    const float4* pred = (const float4*)d_in[0];
    const int4* tgt = (const int4*)d_in[1];
    const int4* wt = (const int4*)d_in[2];
    int n = in_sizes[0];
    int nvec = n / 4;

    float* ws = (float*)d_ws;  // NBLOCKS * 12 floats

    wdice_partial<<<NBLOCKS, NTHREADS, 0, stream>>>(pred, tgt, wt, nvec, ws);
    wdice_final<<<1, NTHREADS, 0, stream>>>(ws, NBLOCKS, (float*)d_out);
}

// Round 7
// 128.988 us; speedup vs baseline: 1.7734x; 1.1863x over previous
//
#include <hip/hip_runtime.h>

#define NSEG 6
#define NBLOCKS 2048
#define NTHREADS 256

typedef int vint4 __attribute__((ext_vector_type(4)));

__global__ __launch_bounds__(NTHREADS) void wdice_partial(
    const float4* __restrict__ pred,
    const vint4* __restrict__ tgt,
    const vint4* __restrict__ wt,
    int nvec,
    float* __restrict__ psum_out,   // [NBLOCKS*NSEG]
    float* __restrict__ cnt_out)    // [NBLOCKS*NSEG]
{
    float ps[NSEG];
    float cn[NSEG];
#pragma unroll
    for (int s = 0; s < NSEG; ++s) { ps[s] = 0.f; cn[s] = 0.f; }

    int tid = blockIdx.x * blockDim.x + threadIdx.x;
    int stride = gridDim.x * blockDim.x;
    for (int i = tid; i < nvec; i += stride) {
        float4 p = pred[i];                              // cacheable: stays L3-resident
        vint4 t = __builtin_nontemporal_load(&tgt[i]);   // nt: stream from HBM, don't pollute caches
        vint4 w = __builtin_nontemporal_load(&wt[i]);    // nt: stream from HBM
        int seg0 = t.x * 3 + w.x;
        int seg1 = t.y * 3 + w.y;
        int seg2 = t.z * 3 + w.z;
        int seg3 = t.w * 3 + w.w;
#pragma unroll
        for (int s = 0; s < NSEG; ++s) {
            if (seg0 == s) { ps[s] += p.x; cn[s] += 1.f; }
            if (seg1 == s) { ps[s] += p.y; cn[s] += 1.f; }
            if (seg2 == s) { ps[s] += p.z; cn[s] += 1.f; }
            if (seg3 == s) { ps[s] += p.w; cn[s] += 1.f; }
        }
    }

    // wave (64-lane) shuffle reduction
#pragma unroll
    for (int s = 0; s < NSEG; ++s) {
#pragma unroll
        for (int off = 32; off > 0; off >>= 1) {
            ps[s] += __shfl_down(ps[s], off, 64);
            cn[s] += __shfl_down(cn[s], off, 64);
        }
    }

    __shared__ float lps[4][NSEG];
    __shared__ float lcn[4][NSEG];
    int lane = threadIdx.x & 63;
    int wave = threadIdx.x >> 6;
    if (lane == 0) {
#pragma unroll
        for (int s = 0; s < NSEG; ++s) { lps[wave][s] = ps[s]; lcn[wave][s] = cn[s]; }
    }
    __syncthreads();
    if (threadIdx.x == 0) {
#pragma unroll
        for (int s = 0; s < NSEG; ++s) {
            float tps = lps[0][s] + lps[1][s] + lps[2][s] + lps[3][s];
            float tcn = lcn[0][s] + lcn[1][s] + lcn[2][s] + lcn[3][s];
            psum_out[blockIdx.x * NSEG + s] = tps;
            cnt_out[blockIdx.x * NSEG + s] = tcn;
        }
    }
}

__global__ __launch_bounds__(NTHREADS) void wdice_final(
    const float* __restrict__ psum_in,
    const float* __restrict__ cnt_in,
    int nrows,
    float* __restrict__ out)
{
    double ps[NSEG];
    double cn[NSEG];
#pragma unroll
    for (int s = 0; s < NSEG; ++s) { ps[s] = 0.0; cn[s] = 0.0; }

    for (int r = threadIdx.x; r < nrows; r += blockDim.x) {
#pragma unroll
        for (int s = 0; s < NSEG; ++s) {
            ps[s] += (double)psum_in[r * NSEG + s];
            cn[s] += (double)cnt_in[r * NSEG + s];
        }
    }

#pragma unroll
    for (int s = 0; s < NSEG; ++s) {
#pragma unroll
        for (int off = 32; off > 0; off >>= 1) {
            ps[s] += __shfl_down(ps[s], off, 64);
            cn[s] += __shfl_down(cn[s], off, 64);
        }
    }

    __shared__ double lps[4][NSEG];
    __shared__ double lcn[4][NSEG];
    int lane = threadIdx.x & 63;
    int wave = threadIdx.x >> 6;
    if (lane == 0) {
#pragma unroll
        for (int s = 0; s < NSEG; ++s) { lps[wave][s] = ps[s]; lcn[wave][s] = cn[s]; }
    }
    __syncthreads();
    if (threadIdx.x == 0) {
        double numer = 0.0, denom = 0.0;
#pragma unroll
        for (int s = 0; s < NSEG; ++s) {
            double tps = lps[0][s] + lps[1][s] + lps[2][s] + lps[3][s];
            double tcn = lcn[0][s] + lcn[1][s] + lcn[2][s] + lcn[3][s];
            if (tcn > 0.0) {
                double inv_n2 = 1.0 / (tcn * tcn);
                numer += tps * inv_n2;
                denom += (tps + tcn) * inv_n2;
            }
        }
        out[0] = (float)(1.0 - 2.0 * numer / denom);
    }
}

extern "C" void kernel_launch(void* const* d_in, const int* in_sizes, int n_in,
                              void* d_out, int out_size, void* d_ws, size_t ws_size,
                              hipStream_t stream) {
    const float4* pred = (const float4*)d_in[0];
    const vint4* tgt = (const vint4*)d_in[1];
    const vint4* wt = (const vint4*)d_in[2];
    int n = in_sizes[0];
    int nvec = n / 4;

    float* psum_ws = (float*)d_ws;
    float* cnt_ws = psum_ws + NBLOCKS * NSEG;

    wdice_partial<<<NBLOCKS, NTHREADS, 0, stream>>>(pred, tgt, wt, nvec, psum_ws, cnt_ws);
    wdice_final<<<1, NTHREADS, 0, stream>>>(psum_ws, cnt_ws, NBLOCKS, (float*)d_out);
}